// Round 11
// baseline (335.086 us; speedup 1.0000x reference)
//
#include <hip/hip_runtime.h>

#define TT 512
#define DD 16
#define HH 30
#define LL 10
#define C  4                  // timesteps per phase
#define TCH (TT / C)          // 128 chunks
#define SKEW 4                // intra-stage pipeline skew (5 waves)
#define PHS (TCH + SKEW)      // 132 local phases per stage
#define WRH 40                // halfs per batch-row in LDS (80 B)
#define GRP 16                // batches per group = MFMA N
#define BLOCKT 320            // 5 waves; wave = local pipeline stage
#define NGRP 64               // batch groups
#define RING 4                // ring slots (chunks) per group
#define KPRE 2.885390081777927f   // 2*log2(e): weights prescaled so exp2(d) = e^(2*preact)

typedef _Float16 f16x8 __attribute__((ext_vector_type(8)));
typedef float    f32x4 __attribute__((ext_vector_type(4)));

union U128 { uint4 u; f16x8 h; unsigned long long q[2]; };

// LDS act links: [2][4 dest-slots][C][GRP][WRH]
#define ACTOFF(par, slot, cc) ((((par) * 4 + (slot)) * C + (cc)) * (GRP * WRH))

// tanh(x) = 1 - 2/(e^2x+1); d = KPRE*x so e^2x = exp2(d). 2 trans + 2 VALU.
__device__ __forceinline__ _Float16 tanh_e(float d) {
    const float e = __builtin_amdgcn_exp2f(d);
    return (_Float16)(1.0f - 2.0f * __builtin_amdgcn_rcpf(e + 1.0f));
}

// Raw pipeline barrier: drain LDS ops only; global traffic stays in flight.
__device__ __forceinline__ void pipe_barrier() {
    __builtin_amdgcn_sched_barrier(0);
    asm volatile("s_waitcnt lgkmcnt(0)" ::: "memory");
    __builtin_amdgcn_sched_barrier(0);
    __builtin_amdgcn_s_barrier();
    __builtin_amdgcn_sched_barrier(0);
    asm volatile("" ::: "memory");
}

// k-position -> natural neuron permutation (MFMA D == next B-own fragment).
__device__ __forceinline__ int nu_of(int k) {
    return 16 * ((k >> 2) & 1) + 4 * (k >> 3) + (k & 3);
}

#define ALOAD(p)    __hip_atomic_load((p),  __ATOMIC_RELAXED, __HIP_MEMORY_SCOPE_AGENT)
#define ASTORE(p,v) __hip_atomic_store((p), (v), __ATOMIC_RELAXED, __HIP_MEMORY_SCOPE_AGENT)

__global__ __launch_bounds__(BLOCKT) void rnn_stage(
    const float* __restrict__ x,   const float* __restrict__ wi0,
    const float* __restrict__ wih, const float* __restrict__ whh,
    const float* __restrict__ bih, const float* __restrict__ bhh,
    const float* __restrict__ fcw, const float* __restrict__ fcb,
    float* __restrict__ out, unsigned* __restrict__ flags,
    unsigned long long* __restrict__ ring)
{
    __shared__ __align__(16) _Float16 act[2 * 4 * C * GRP * WRH]; // 40960 B

    const int tid   = threadIdx.x;
    const int w     = tid >> 6;        // wave 0..4 (local pipeline stage)
    const int lane  = tid & 63;
    const int n     = lane & 15;       // batch-in-group
    const int qq    = lane >> 4;       // k-slice / D row-group
    const int g     = blockIdx.x & (NGRP - 1);
    const int stage = blockIdx.x >> 6; // 0: layers 0-4, 1: layers 5-9
    const int l     = stage * 5 + w;   // global layer
    const int b0    = g * GRP;

    unsigned* fl = flags + g;          // chunks produced (stage-0 wave-4 -> stage-1 wave-0)
    unsigned* cf = flags + NGRP + g;   // chunks consumed
    // ring element (slot, cc, n, qq): u64 index
    unsigned long long* rg = ring + (size_t)g * (RING * C * GRP * 8);
#define RIDX(slot, cc) ((((slot) * C + (cc)) * GRP + n) * 8 + qq * 2)

    // ---- A-frags, prescaled by KPRE. A[m][k]: m=16*tile+n, kpos=8qq+i ----
    f16x8 wain[2], waown[2];
    #pragma unroll
    for (int tile = 0; tile < 2; ++tile) {
        const int j = 16 * tile + n;
        #pragma unroll
        for (int i = 0; i < 8; ++i) {
            const int kap = 8 * qq + i;
            const int nu  = nu_of(kap);
            float vi = 0.f, vo = 0.f;
            if (j < HH) {
                if (l == 0) { if (kap < DD) vi = wi0[j * DD + kap]; }
                else        { if (nu  < HH) vi = wih[(l - 1) * 900 + j * HH + nu]; }
                if (nu < HH) vo = whh[l * 900 + j * HH + nu];
            }
            wain[tile][i]  = (_Float16)(vi * KPRE);
            waown[tile][i] = (_Float16)(vo * KPRE);
        }
    }
    f32x4 cb[2];
    #pragma unroll
    for (int tile = 0; tile < 2; ++tile)
        #pragma unroll
        for (int r = 0; r < 4; ++r) {
            const int j2 = 16 * tile + 4 * qq + r;
            cb[tile][r] = (j2 < HH) ? (bih[l * HH + j2] + bhh[l * HH + j2]) * KPRE : 0.f;
        }
    float fcl[8];
    #pragma unroll
    for (int i = 0; i < 8; ++i) {
        const int nu = nu_of(8 * qq + i);
        fcl[i] = (nu < HH) ? fcw[nu] : 0.f;   // NOT prescaled (applied to h)
    }
    const float fbv = fcb[0];

    // ---- stage-0 wave-0 x prefetch ----
    float4 xb[C][2];
    const float4* x4 = (const float4*)x;
    const size_t xbase = (size_t)(b0 + n) * TT * 4;
    if (stage == 0 && w == 0 && qq < 2) {
        #pragma unroll
        for (int cc = 0; cc < C; ++cc) {
            xb[cc][0] = x4[xbase + cc * 4 + 2 * qq];
            xb[cc][1] = x4[xbase + cc * 4 + 2 * qq + 1];
        }
    }

    // ---- stage-1 wave-0: preload ring chunk 0 into regs ----
    U128 rin[C];
    if (stage == 1 && w == 0) {
        while ((int)ALOAD(fl) < 1) {}
        asm volatile("" ::: "memory");
        #pragma unroll
        for (int cc = 0; cc < C; ++cc) {
            rin[cc].q[0] = ALOAD(rg + RIDX(0, cc));
            rin[cc].q[1] = ALOAD(rg + RIDX(0, cc) + 1);
        }
    }

    // recurrent state, register-resident: h(-1) = 0
    f16x8 bown;
    #pragma unroll
    for (int i = 0; i < 8; ++i) bown[i] = (_Float16)0.f;

    __syncthreads();

    for (int p = 0; p < PHS; ++p) {
        const int pt = p - w;         // this wave's chunk index
        const int q  = (p + 1) & 1;   // read parity
        const int wp = p & 1;         // write parity

        if (0 <= pt && pt < TCH) {
            // ---- backpressure: producer must not overwrite unconsumed slot ----
            if (stage == 0 && w == 4 && pt >= RING) {
                while ((int)ALOAD(cf) < pt - RING + 1) {}
                asm volatile("" ::: "memory");
            }

            // ---- stage all C input fragments ----
            U128 binu[C];
            if (stage == 0 && w == 0) {
                #pragma unroll
                for (int cc = 0; cc < C; ++cc) {
                    if (qq < 2) {
                        const float4 u = xb[cc][0], v = xb[cc][1];
                        binu[cc].h[0] = (_Float16)u.x; binu[cc].h[1] = (_Float16)u.y;
                        binu[cc].h[2] = (_Float16)u.z; binu[cc].h[3] = (_Float16)u.w;
                        binu[cc].h[4] = (_Float16)v.x; binu[cc].h[5] = (_Float16)v.y;
                        binu[cc].h[6] = (_Float16)v.z; binu[cc].h[7] = (_Float16)v.w;
                        if (p + 1 < TCH) {
                            const int tn = (p + 1) * C + cc;
                            xb[cc][0] = x4[xbase + tn * 4 + 2 * qq];
                            xb[cc][1] = x4[xbase + tn * 4 + 2 * qq + 1];
                        }
                    } else {
                        binu[cc].u = uint4{0u, 0u, 0u, 0u};
                    }
                }
            } else if (stage == 1 && w == 0) {
                #pragma unroll
                for (int cc = 0; cc < C; ++cc) binu[cc] = rin[cc];  // consume regs
                if (pt + 1 < TCH) {            // prefetch next chunk (latency hidden)
                    while ((int)ALOAD(fl) < pt + 2) {}
                    asm volatile("" ::: "memory");
                    const int sl = (pt + 1) & (RING - 1);
                    #pragma unroll
                    for (int cc = 0; cc < C; ++cc) {
                        rin[cc].q[0] = ALOAD(rg + RIDX(sl, cc));
                        rin[cc].q[1] = ALOAD(rg + RIDX(sl, cc) + 1);
                    }
                }
            } else {
                #pragma unroll
                for (int cc = 0; cc < C; ++cc)
                    binu[cc].u = *(const uint4*)(act + ACTOFF(q, w - 1, cc)
                                                 + n * WRH + 8 * qq);
            }

            // ---- input-side MFMAs: independent, issue early ----
            f32x4 dp0[C], dp1[C];
            #pragma unroll
            for (int cc = 0; cc < C; ++cc) {
                dp0[cc] = __builtin_amdgcn_mfma_f32_16x16x32_f16(wain[0], binu[cc].h, cb[0], 0, 0, 0);
                dp1[cc] = __builtin_amdgcn_mfma_f32_16x16x32_f16(wain[1], binu[cc].h, cb[1], 0, 0, 0);
            }

            // ---- serial own-chain: mfma -> tanh -> pack, state in VGPRs ----
            #pragma unroll
            for (int cc = 0; cc < C; ++cc) {
                const f32x4 d0 = __builtin_amdgcn_mfma_f32_16x16x32_f16(waown[0], bown, dp0[cc], 0, 0, 0);
                const f32x4 d1 = __builtin_amdgcn_mfma_f32_16x16x32_f16(waown[1], bown, dp1[cc], 0, 0, 0);
                f16x8 nb;
                #pragma unroll
                for (int r = 0; r < 4; ++r) {
                    nb[r]     = tanh_e(d0[r]);
                    nb[4 + r] = tanh_e(d1[r]);
                }
                bown = nb;
                if (w < 4) {                       // intra-block LDS handoff
                    U128 uu; uu.h = nb;
                    *(uint4*)(act + ACTOFF(wp, w, cc) + n * WRH + 8 * qq) = uu.u;
                } else if (stage == 0) {           // ring store (write-through)
                    U128 uu; uu.h = nb;
                    const int sl = pt & (RING - 1);
                    ASTORE(rg + RIDX(sl, cc),     uu.q[0]);
                    ASTORE(rg + RIDX(sl, cc) + 1, uu.q[1]);
                }
            }

            // ---- handshake publishes ----
            if (stage == 0 && w == 4) {
                asm volatile("s_waitcnt vmcnt(0)" ::: "memory"); // data before flag
                if (lane == 0) ASTORE(fl, (unsigned)(pt + 1));
            }
            if (stage == 1 && w == 0) {
                if (lane == 0) ASTORE(cf, (unsigned)(pt + 1));
            }
        }
        pipe_barrier();               // lgkm drain only
    }

    // ---- FC on h_9(T-1): stage-1 wave-4 ----
    if (stage == 1 && w == 4) {
        float v = 0.f;
        #pragma unroll
        for (int i = 0; i < 8; ++i) v = fmaf((float)bown[i], fcl[i], v);
        v += __shfl_xor(v, 16);
        v += __shfl_xor(v, 32);
        if (qq == 0) out[b0 + n] = v + fbv;
    }
}

extern "C" void kernel_launch(void* const* d_in, const int* in_sizes, int n_in,
                              void* d_out, int out_size, void* d_ws, size_t ws_size,
                              hipStream_t stream) {
    const float* x   = (const float*)d_in[0];
    const float* wi0 = (const float*)d_in[1];
    const float* wih = (const float*)d_in[2];
    const float* whh = (const float*)d_in[3];
    const float* bih = (const float*)d_in[4];
    const float* bhh = (const float*)d_in[5];
    const float* fcw = (const float*)d_in[6];
    const float* fcb = (const float*)d_in[7];
    float* out = (float*)d_out;

    unsigned* flags = (unsigned*)d_ws;                       // 2*NGRP u32
    unsigned long long* ring =
        (unsigned long long*)((char*)d_ws + 1024);           // 1 MiB ring

    hipMemsetAsync(d_ws, 0, 1024, stream);                   // zero flags (capture-safe)

    rnn_stage<<<2 * NGRP, BLOCKT, 0, stream>>>(x, wi0, wih, whh, bih, bhh,
                                               fcw, fcb, out, flags, ring);
}

// Round 12
// 225.439 us; speedup vs baseline: 1.4864x; 1.4864x over previous
//
#include <hip/hip_runtime.h>

#define TT 512
#define DD 16
#define HH 30
#define LL 10
#define C  4                  // timesteps per chunk
#define TCH (TT / C)          // 128 chunks
#define RING 3                // slots per link (drift budget +-2 chunks)
#define WRH 40                // halfs per batch-row (80 B): 32 data + pad
#define GRP 16                // batches per block = MFMA N
#define BLOCKT (LL * 64)      // 640 threads, wave = layer
#define KPRE 2.885390081777927f   // 2*log2(e): prescale so exp2(d) = e^(2*preact)

typedef _Float16 f16x8 __attribute__((ext_vector_type(8)));
typedef float    f32x4 __attribute__((ext_vector_type(4)));

union U128 { uint4 u; f16x8 h; };

// link l (wave l -> l+1), slot sl, chunk-step cc: [GRP][WRH] halfs
#define LINKOFF(l, sl, cc) ((((l) * RING + (sl)) * C + (cc)) * (GRP * WRH))

// tanh(x) = 1 - 2/(e^2x+1); d = KPRE*x prefolded into weights/bias.
__device__ __forceinline__ _Float16 tanh_e(float d) {
    const float e = __builtin_amdgcn_exp2f(d);
    return (_Float16)(1.0f - 2.0f * __builtin_amdgcn_rcpf(e + 1.0f));
}

// k-position -> natural neuron permutation (MFMA D == next B-own fragment).
__device__ __forceinline__ int nu_of(int k) {
    return 16 * ((k >> 2) & 1) + 4 * (k >> 3) + (k & 3);
}

__device__ __forceinline__ void wait_ge(unsigned* f, unsigned tgt) {
    while (__hip_atomic_load(f, __ATOMIC_ACQUIRE,
                             __HIP_MEMORY_SCOPE_WORKGROUP) < tgt)
        __builtin_amdgcn_s_sleep(1);
}

__global__ __launch_bounds__(BLOCKT) void rnn_flow(
    const float* __restrict__ x,   const float* __restrict__ wi0,
    const float* __restrict__ wih, const float* __restrict__ whh,
    const float* __restrict__ bih, const float* __restrict__ bhh,
    const float* __restrict__ fcw, const float* __restrict__ fcb,
    float* __restrict__ out)
{
    extern __shared__ __align__(16) _Float16 link[]; // [LL-1][RING][C][GRP][WRH] = 138240 B
    __shared__ unsigned flg[2 * LL];  // [0..9]=done (link l), [10..19]=cons (link l-1 by wave l)

    const int tid  = threadIdx.x;
    const int l    = tid >> 6;        // wave == layer
    const int lane = tid & 63;
    const int n    = lane & 15;       // batch-in-group (B col / D col / A m-row)
    const int qq   = lane >> 4;       // k-slice / D row-group
    const int b0   = blockIdx.x * GRP;

    // ---- A-frags, prescaled by KPRE. A[m][k]: m=16*tile+n, kpos=8qq+i;
    //      column = neuron nu_of(kpos) (permuted), except layer-0 x (natural).
    f16x8 wain[2], waown[2];
    #pragma unroll
    for (int tile = 0; tile < 2; ++tile) {
        const int j = 16 * tile + n;
        #pragma unroll
        for (int i = 0; i < 8; ++i) {
            const int kap = 8 * qq + i;
            const int nu  = nu_of(kap);
            float vi = 0.f, vo = 0.f;
            if (j < HH) {
                if (l == 0) { if (kap < DD) vi = wi0[j * DD + kap]; }
                else        { if (nu  < HH) vi = wih[(l - 1) * 900 + j * HH + nu]; }
                if (nu < HH) vo = whh[l * 900 + j * HH + nu];
            }
            wain[tile][i]  = (_Float16)(vi * KPRE);
            waown[tile][i] = (_Float16)(vo * KPRE);
        }
    }
    f32x4 cb[2];
    #pragma unroll
    for (int tile = 0; tile < 2; ++tile)
        #pragma unroll
        for (int r = 0; r < 4; ++r) {
            const int j2 = 16 * tile + 4 * qq + r;
            cb[tile][r] = (j2 < HH) ? (bih[l * HH + j2] + bhh[l * HH + j2]) * KPRE : 0.f;
        }
    float fcl[8];
    #pragma unroll
    for (int i = 0; i < 8; ++i) {
        const int nu = nu_of(8 * qq + i);
        fcl[i] = (nu < HH) ? fcw[nu] : 0.f;   // applied to h, not prescaled
    }
    const float fbv = fcb[0];

    // ---- wave-0 x prefetch: xb[cc] = x[b0+n][t=chunk*C+cc][8qq..8qq+7] ----
    float4 xb[C][2];
    const float4* x4 = (const float4*)x;
    const size_t xbase = (size_t)(b0 + n) * TT * 4;
    if (l == 0 && qq < 2) {
        #pragma unroll
        for (int cc = 0; cc < C; ++cc) {
            xb[cc][0] = x4[xbase + cc * 4 + 2 * qq];
            xb[cc][1] = x4[xbase + cc * 4 + 2 * qq + 1];
        }
    }

    // recurrent state, register-resident: h(-1) = 0
    f16x8 bown;
    #pragma unroll
    for (int i = 0; i < 8; ++i) bown[i] = (_Float16)0.f;

    if (tid < 2 * LL) flg[tid] = 0u;
    __syncthreads();                  // the only block-wide barrier

    unsigned sl = 0;                  // slot = pt % RING, tracked incrementally
    for (int pt = 0; pt < TCH; ++pt) {
        // ---- acquire + load input chunk pt ----
        U128 binu[C];
        if (l == 0) {
            #pragma unroll
            for (int cc = 0; cc < C; ++cc) {
                if (qq < 2) {
                    const float4 u = xb[cc][0], v = xb[cc][1];
                    binu[cc].h[0] = (_Float16)u.x; binu[cc].h[1] = (_Float16)u.y;
                    binu[cc].h[2] = (_Float16)u.z; binu[cc].h[3] = (_Float16)u.w;
                    binu[cc].h[4] = (_Float16)v.x; binu[cc].h[5] = (_Float16)v.y;
                    binu[cc].h[6] = (_Float16)v.z; binu[cc].h[7] = (_Float16)v.w;
                    if (pt + 1 < TCH) {        // rolling refill, 1 chunk ahead
                        const int tn = (pt + 1) * C + cc;
                        xb[cc][0] = x4[xbase + tn * 4 + 2 * qq];
                        xb[cc][1] = x4[xbase + tn * 4 + 2 * qq + 1];
                    }
                } else {
                    binu[cc].u = uint4{0u, 0u, 0u, 0u};
                }
            }
        } else {
            wait_ge(&flg[l - 1], (unsigned)(pt + 1));      // producer done
            #pragma unroll
            for (int cc = 0; cc < C; ++cc)
                binu[cc].u = *(const uint4*)(link + LINKOFF(l - 1, sl, cc)
                                             + n * WRH + 8 * qq);
        }

        // ---- input-side MFMAs: independent, issue early ----
        f32x4 dp0[C], dp1[C];
        #pragma unroll
        for (int cc = 0; cc < C; ++cc) {
            dp0[cc] = __builtin_amdgcn_mfma_f32_16x16x32_f16(wain[0], binu[cc].h, cb[0], 0, 0, 0);
            dp1[cc] = __builtin_amdgcn_mfma_f32_16x16x32_f16(wain[1], binu[cc].h, cb[1], 0, 0, 0);
        }
        // publish consumption (release waits our ds_reads via lgkmcnt(0))
        if (l > 0 && lane == 0)
            __hip_atomic_store(&flg[LL + l], (unsigned)(pt + 1),
                               __ATOMIC_RELEASE, __HIP_MEMORY_SCOPE_WORKGROUP);

        // ---- gate slot reuse: consumer must be done with chunk pt-RING ----
        if (l < LL - 1 && pt >= RING)
            wait_ge(&flg[LL + l + 1], (unsigned)(pt - RING + 1));

        // ---- serial own-chain: mfma -> tanh -> pack, state in VGPRs ----
        #pragma unroll
        for (int cc = 0; cc < C; ++cc) {
            const f32x4 d0 = __builtin_amdgcn_mfma_f32_16x16x32_f16(waown[0], bown, dp0[cc], 0, 0, 0);
            const f32x4 d1 = __builtin_amdgcn_mfma_f32_16x16x32_f16(waown[1], bown, dp1[cc], 0, 0, 0);
            f16x8 nb;
            #pragma unroll
            for (int r = 0; r < 4; ++r) {
                nb[r]     = tanh_e(d0[r]);
                nb[4 + r] = tanh_e(d1[r]);
            }
            bown = nb;
            if (l < LL - 1) {                  // handoff: contiguous b128
                U128 uu; uu.h = nb;
                *(uint4*)(link + LINKOFF(l, sl, cc) + n * WRH + 8 * qq) = uu.u;
            }
        }
        // publish production (release waits our ds_writes via lgkmcnt(0))
        if (l < LL - 1 && lane == 0)
            __hip_atomic_store(&flg[l], (unsigned)(pt + 1),
                               __ATOMIC_RELEASE, __HIP_MEMORY_SCOPE_WORKGROUP);

        sl = (sl == RING - 1) ? 0u : sl + 1u;
    }

    // ---- FC on h_9(T-1), register-resident in wave 9's bown ----
    if (l == LL - 1) {
        float v = 0.f;
        #pragma unroll
        for (int i = 0; i < 8; ++i) v = fmaf((float)bown[i], fcl[i], v);
        v += __shfl_xor(v, 16);      // combine the four qq k-slices
        v += __shfl_xor(v, 32);
        if (qq == 0) out[b0 + n] = v + fbv;
    }
}

extern "C" void kernel_launch(void* const* d_in, const int* in_sizes, int n_in,
                              void* d_out, int out_size, void* d_ws, size_t ws_size,
                              hipStream_t stream) {
    const float* x   = (const float*)d_in[0];
    const float* wi0 = (const float*)d_in[1];
    const float* wih = (const float*)d_in[2];
    const float* whh = (const float*)d_in[3];
    const float* bih = (const float*)d_in[4];
    const float* bhh = (const float*)d_in[5];
    const float* fcw = (const float*)d_in[6];
    const float* fcb = (const float*)d_in[7];
    float* out = (float*)d_out;

    const size_t lds_bytes =
        (size_t)((LL - 1) * RING * C * GRP * WRH) * sizeof(_Float16); // 138240 B
    hipFuncSetAttribute((const void*)rnn_flow,
                        hipFuncAttributeMaxDynamicSharedMemorySize,
                        (int)lds_bytes);

    rnn_flow<<<1024 / GRP, BLOCKT, lds_bytes, stream>>>(x, wi0, wih, whh,
                                                        bih, bhh, fcw, fcb, out);
}

// Round 13
// 204.381 us; speedup vs baseline: 1.6395x; 1.1030x over previous
//
#include <hip/hip_runtime.h>

#define TT 512
#define DD 16
#define HH 30
#define LL 10
#define C  4                  // timesteps per chunk
#define TCH (TT / C)          // 128 chunks
#define RING 4                // slots per link; sl = pt & 3 (static via unroll)
#define GRP 16                // batches per block = MFMA N
#define BLOCKT (LL * 64)      // 640 threads, wave = layer
#define KPRE 2.885390081777927f   // 2*log2(e)

// LDS strides in halfs: per-(sl,cc) tile = 64 lanes x 8 halfs (contiguous 16B/lane)
#define CC_H   512
#define SL_H   (C * CC_H)     // 2048
#define LINK_H (RING * SL_H)  // 8192

typedef _Float16 f16x8 __attribute__((ext_vector_type(8)));
typedef _Float16 h2    __attribute__((ext_vector_type(2)));
typedef float    f32x4 __attribute__((ext_vector_type(4)));

union U128 { uint4 u; f16x8 h; h2 p[4]; };

// sigma(d) = 1/(exp2(d)+1);  h = 1 - 2*sigma folded into consumer weights/bias.
__device__ __forceinline__ float sigma_e(float d) {
    const float e = __builtin_amdgcn_exp2f(d);
    return __builtin_amdgcn_rcpf(e + 1.0f);
}

// k-position -> natural neuron permutation (MFMA D == next B-own fragment).
__device__ __forceinline__ int nu_of(int k) {
    return 16 * ((k >> 2) & 1) + 4 * (k >> 3) + (k & 3);
}

__device__ __forceinline__ void wait_ge(unsigned* f, unsigned tgt) {
    while (__hip_atomic_load(f, __ATOMIC_ACQUIRE,
                             __HIP_MEMORY_SCOPE_WORKGROUP) < tgt)
        __builtin_amdgcn_s_sleep(1);
}

__global__ __launch_bounds__(BLOCKT) void rnn_sig(
    const float* __restrict__ x,   const float* __restrict__ wi0,
    const float* __restrict__ wih, const float* __restrict__ whh,
    const float* __restrict__ bih, const float* __restrict__ bhh,
    const float* __restrict__ fcw, const float* __restrict__ fcb,
    float* __restrict__ out)
{
    extern __shared__ __align__(16) _Float16 link[]; // [LL-1][RING][C][512h] = 147456 B
    __shared__ unsigned flg[2 * LL];  // [l]=produced(link l), [LL+l]=consumed(link l-1)

    const int tid  = threadIdx.x;
    const int l    = tid >> 6;        // wave == layer
    const int lane = tid & 63;
    const int n    = lane & 15;       // batch-in-group
    const int qq   = lane >> 4;       // k-slice / D row-group
    const int b0   = blockIdx.x * GRP;

    // ---- A-frags: sigma-folded (-2W) for sigma-encoded operands, KPRE-prescaled.
    //      Layer-0 input (x) stays natural (+W). Column permuted by nu_of.
    f16x8 wain[2], waown[2];
    #pragma unroll
    for (int tile = 0; tile < 2; ++tile) {
        const int j = 16 * tile + n;
        #pragma unroll
        for (int i = 0; i < 8; ++i) {
            const int kap = 8 * qq + i;
            const int nu  = nu_of(kap);
            float vi = 0.f, vo = 0.f;
            if (j < HH) {
                if (l == 0) { if (kap < DD) vi =  wi0[j * DD + kap]; }
                else        { if (nu  < HH) vi = -2.f * wih[(l - 1) * 900 + j * HH + nu]; }
                if (nu < HH) vo = -2.f * whh[l * 900 + j * HH + nu];
            }
            wain[tile][i]  = (_Float16)(vi * KPRE);
            waown[tile][i] = (_Float16)(vo * KPRE);
        }
    }
    // ---- bias C-init: KPRE*(b_ih + b_hh + rowsum(Whh) + (l>0 ? rowsum(Wih) : 0))
    f32x4 cb[2];
    #pragma unroll
    for (int tile = 0; tile < 2; ++tile)
        #pragma unroll
        for (int r = 0; r < 4; ++r) {
            const int j2 = 16 * tile + 4 * qq + r;
            float v = 0.f;
            if (j2 < HH) {
                v = bih[l * HH + j2] + bhh[l * HH + j2];
                for (int k = 0; k < HH; ++k) v += whh[l * 900 + j2 * HH + k];
                if (l > 0)
                    for (int k = 0; k < HH; ++k) v += wih[(l - 1) * 900 + j2 * HH + k];
            }
            cb[tile][r] = v * KPRE;
        }
    // ---- FC folded: out = (sum(fcw)+fcb) + sum(-2 fcw * sigma)
    float fcl[8];
    #pragma unroll
    for (int i = 0; i < 8; ++i) {
        const int nu = nu_of(8 * qq + i);
        fcl[i] = (nu < HH) ? -2.f * fcw[nu] : 0.f;
    }
    float fbv = fcb[0];
    for (int k = 0; k < HH; ++k) fbv += fcw[k];

    // ---- wave-0 x prefetch: xb[cc] = x[b0+n][t=chunk*C+cc][8qq..8qq+7] ----
    float4 xb[C][2];
    const float4* x4 = (const float4*)x;
    const size_t xbase = (size_t)(b0 + n) * TT * 4;
    if (l == 0 && qq < 2) {
        #pragma unroll
        for (int cc = 0; cc < C; ++cc) {
            xb[cc][0] = x4[xbase + cc * 4 + 2 * qq];
            xb[cc][1] = x4[xbase + cc * 4 + 2 * qq + 1];
        }
    }

    // LDS link bases (halfs); per-lane 16B slot at lane*8
    _Float16* lin_r = link + (l - 1) * LINK_H + lane * 8;  // valid for l>0
    _Float16* lin_w = link + l * LINK_H + lane * 8;        // valid for l<9

    // recurrent state: sigma-encoded, sigma(h=0) = 0.5
    f16x8 bown;
    #pragma unroll
    for (int i = 0; i < 8; ++i) bown[i] = (_Float16)0.5f;

    if (tid < 2 * LL) flg[tid] = 0u;
    __syncthreads();                  // the only block-wide barrier

    for (int pb = 0; pb < TCH; pb += RING) {
        #pragma unroll
        for (int sl = 0; sl < RING; ++sl) {       // sl literal -> static offsets
            const int pt = pb + sl;

            // ---- acquire + load input chunk pt ----
            U128 binu[C];
            if (l == 0) {
                #pragma unroll
                for (int cc = 0; cc < C; ++cc) {
                    if (qq < 2) {
                        const float4 u = xb[cc][0], v = xb[cc][1];
                        binu[cc].p[0] = (h2)__builtin_amdgcn_cvt_pkrtz(u.x, u.y);
                        binu[cc].p[1] = (h2)__builtin_amdgcn_cvt_pkrtz(u.z, u.w);
                        binu[cc].p[2] = (h2)__builtin_amdgcn_cvt_pkrtz(v.x, v.y);
                        binu[cc].p[3] = (h2)__builtin_amdgcn_cvt_pkrtz(v.z, v.w);
                        if (pt + 1 < TCH) {        // rolling refill, 1 chunk ahead
                            const int tn = (pt + 1) * C + cc;
                            xb[cc][0] = x4[xbase + tn * 4 + 2 * qq];
                            xb[cc][1] = x4[xbase + tn * 4 + 2 * qq + 1];
                        }
                    } else {
                        binu[cc].u = uint4{0u, 0u, 0u, 0u};
                    }
                }
            } else {
                wait_ge(&flg[l - 1], (unsigned)(pt + 1));      // producer done
                #pragma unroll
                for (int cc = 0; cc < C; ++cc)
                    binu[cc].u = *(const uint4*)(lin_r + sl * SL_H + cc * CC_H);
            }

            // ---- input-side MFMAs: independent, issue early ----
            f32x4 dp0[C], dp1[C];
            #pragma unroll
            for (int cc = 0; cc < C; ++cc) {
                dp0[cc] = __builtin_amdgcn_mfma_f32_16x16x32_f16(wain[0], binu[cc].h, cb[0], 0, 0, 0);
                dp1[cc] = __builtin_amdgcn_mfma_f32_16x16x32_f16(wain[1], binu[cc].h, cb[1], 0, 0, 0);
            }
            // publish consumption (release orders our ds_reads)
            if (l > 0 && lane == 0)
                __hip_atomic_store(&flg[LL + l], (unsigned)(pt + 1),
                                   __ATOMIC_RELEASE, __HIP_MEMORY_SCOPE_WORKGROUP);
            // gate slot reuse: consumer must be done with chunk pt-RING
            if (l < LL - 1 && pt >= RING)
                wait_ge(&flg[LL + l + 1], (unsigned)(pt - RING + 1));

            // ---- serial own-chain: mfma -> sigma -> pack (state in VGPRs) ----
            #pragma unroll
            for (int cc = 0; cc < C; ++cc) {
                const f32x4 d0 = __builtin_amdgcn_mfma_f32_16x16x32_f16(waown[0], bown, dp0[cc], 0, 0, 0);
                const f32x4 d1 = __builtin_amdgcn_mfma_f32_16x16x32_f16(waown[1], bown, dp1[cc], 0, 0, 0);
                U128 uu;
                uu.p[0] = (h2)__builtin_amdgcn_cvt_pkrtz(sigma_e(d0[0]), sigma_e(d0[1]));
                uu.p[1] = (h2)__builtin_amdgcn_cvt_pkrtz(sigma_e(d0[2]), sigma_e(d0[3]));
                uu.p[2] = (h2)__builtin_amdgcn_cvt_pkrtz(sigma_e(d1[0]), sigma_e(d1[1]));
                uu.p[3] = (h2)__builtin_amdgcn_cvt_pkrtz(sigma_e(d1[2]), sigma_e(d1[3]));
                bown = uu.h;
                if (l < LL - 1)
                    *(uint4*)(lin_w + sl * SL_H + cc * CC_H) = uu.u;
            }
            // publish production (release orders our ds_writes)
            if (l < LL - 1 && lane == 0)
                __hip_atomic_store(&flg[l], (unsigned)(pt + 1),
                                   __ATOMIC_RELEASE, __HIP_MEMORY_SCOPE_WORKGROUP);
        }
    }

    // ---- FC on sigma_9(T-1): out = (sum fcw + fcb) + sum(-2 fcw * sigma) ----
    if (l == LL - 1) {
        float v = 0.f;
        #pragma unroll
        for (int i = 0; i < 8; ++i) v = fmaf((float)bown[i], fcl[i], v);
        v += __shfl_xor(v, 16);      // combine the four qq k-slices
        v += __shfl_xor(v, 32);
        if (qq == 0) out[b0 + n] = v + fbv;
    }
}

extern "C" void kernel_launch(void* const* d_in, const int* in_sizes, int n_in,
                              void* d_out, int out_size, void* d_ws, size_t ws_size,
                              hipStream_t stream) {
    const float* x   = (const float*)d_in[0];
    const float* wi0 = (const float*)d_in[1];
    const float* wih = (const float*)d_in[2];
    const float* whh = (const float*)d_in[3];
    const float* bih = (const float*)d_in[4];
    const float* bhh = (const float*)d_in[5];
    const float* fcw = (const float*)d_in[6];
    const float* fcb = (const float*)d_in[7];
    float* out = (float*)d_out;

    const size_t lds_bytes = (size_t)(LL - 1) * LINK_H * sizeof(_Float16); // 147456 B
    hipFuncSetAttribute((const void*)rnn_sig,
                        hipFuncAttributeMaxDynamicSharedMemorySize,
                        (int)lds_bytes);

    rnn_sig<<<1024 / GRP, BLOCKT, lds_bytes, stream>>>(x, wi0, wih, whh,
                                                       bih, bhh, fcw, fcb, out);
}